// Round 1
// baseline (2440.091 us; speedup 1.0000x reference)
//
#include <hip/hip_runtime.h>

// Problem constants
#define Bq 1024
#define Tq 512
#define Fq 64   // input features
#define Hq 128  // hidden
#define Gq 512  // 4*H gates

typedef _Float16 f16;
typedef f16 f16x2 __attribute__((ext_vector_type(2)));

__device__ __forceinline__ float fdot2f(f16x2 a, f16x2 b, float c) {
#if __has_builtin(__builtin_amdgcn_fdot2)
    return __builtin_amdgcn_fdot2(a, b, c, false);
#else
    return c + (float)a.x * (float)b.x + (float)a.y * (float)b.y;
#endif
}

__device__ __forceinline__ f16x2 pack2(float a, float b) {
    f16x2 r; r.x = (f16)a; r.y = (f16)b; return r;
}

__device__ __forceinline__ float sigmoidf_(float x) {
    return 1.f / (1.f + __expf(-x));
}
__device__ __forceinline__ float tanhf_(float x) {
    // safe at both extremes: exp->inf gives 1, exp->0 gives -1
    return 1.f - 2.f / (__expf(2.f * x) + 1.f);
}

union F4H { float4 f4; f16x2 h2[4]; };

__global__ __launch_bounds__(256, 2) void lstm_ae_kernel(
    const float* __restrict__ ts,
    const float* __restrict__ Wih_e, const float* __restrict__ Whh_e,
    const float* __restrict__ bih_e, const float* __restrict__ bhh_e,
    const float* __restrict__ Wih_d, const float* __restrict__ Whh_d,
    const float* __restrict__ bih_d, const float* __restrict__ bhh_d,
    const float* __restrict__ Wout, const float* __restrict__ bout,
    float* __restrict__ out)
{
    const int tid = threadIdx.x;
    const int bid = blockIdx.x;
    const int g0 = tid;        // first owned gate row
    const int g1 = tid + 256;  // second owned gate row
    const int row0 = bid * 2;  // first global batch row of this block

    __shared__ alignas(16) f16x2 x_lds[2][Fq / 2];       // 256 B
    __shared__ alignas(16) f16x2 h_lds[2][Hq / 2];       // 512 B
    __shared__ alignas(16) float gbuf[2][Gq];            // 4 KB
    __shared__ alignas(16) f16x2 wout_lds[Hq / 2][Fq];   // [p][f], 16 KB
    __shared__ float bvals[1];                            // unused pad
    (void)bvals;

    // Register-resident weights: 2 gate rows, packed f16 pairs.
    f16x2 wih[2][Fq / 2];  // 64 VGPRs
    f16x2 whh[2][Hq / 2];  // 128 VGPRs
    float bias0, bias1;

    auto load_weights = [&](const float* __restrict__ Wih,
                            const float* __restrict__ Whh,
                            const float* __restrict__ bih,
                            const float* __restrict__ bhh) {
#pragma unroll
        for (int k = 0; k < Fq / 2; ++k) {
            float2 a = *(const float2*)(Wih + (size_t)g0 * Fq + 2 * k);
            float2 b = *(const float2*)(Wih + (size_t)g1 * Fq + 2 * k);
            wih[0][k] = pack2(a.x, a.y);
            wih[1][k] = pack2(b.x, b.y);
        }
#pragma unroll
        for (int k = 0; k < Hq / 2; ++k) {
            float2 a = *(const float2*)(Whh + (size_t)g0 * Hq + 2 * k);
            float2 b = *(const float2*)(Whh + (size_t)g1 * Hq + 2 * k);
            whh[0][k] = pack2(a.x, a.y);
            whh[1][k] = pack2(b.x, b.y);
        }
        bias0 = bih[g0] + bhh[g0];
        bias1 = bih[g1] + bhh[g1];
    };

    // gates for one batch row: reads x_lds/h_lds (wave-broadcast), writes gbuf
    auto gates_row = [&](int row) {
        float a0 = bias0, a1 = bias1;
        const float4* xp = (const float4*)(&x_lds[row][0]);  // 8 x float4
#pragma unroll
        for (int k4 = 0; k4 < Fq / 8; ++k4) {
            F4H u; u.f4 = xp[k4];
#pragma unroll
            for (int i = 0; i < 4; ++i) {
                a0 = fdot2f(wih[0][k4 * 4 + i], u.h2[i], a0);
                a1 = fdot2f(wih[1][k4 * 4 + i], u.h2[i], a1);
            }
        }
        const float4* hp = (const float4*)(&h_lds[row][0]);  // 16 x float4
#pragma unroll
        for (int k4 = 0; k4 < Hq / 8; ++k4) {
            F4H u; u.f4 = hp[k4];
#pragma unroll
            for (int i = 0; i < 4; ++i) {
                a0 = fdot2f(whh[0][k4 * 4 + i], u.h2[i], a0);
                a1 = fdot2f(whh[1][k4 * 4 + i], u.h2[i], a1);
            }
        }
        gbuf[row][g0] = a0;
        gbuf[row][g1] = a1;
    };

    // LSTM pointwise update; each thread owns one (row, j) unit, c in register
    const int urow = tid >> 7;     // 0..1
    const int uj = tid & 127;      // hidden index
    float c_reg = 0.f;

    auto update_hc = [&]() {
        float gi = gbuf[urow][uj];
        float gf = gbuf[urow][uj + 128];
        float gg = gbuf[urow][uj + 256];
        float go = gbuf[urow][uj + 384];
        float i_ = sigmoidf_(gi);
        float f_ = sigmoidf_(gf);
        float g_ = tanhf_(gg);
        float o_ = sigmoidf_(go);
        c_reg = f_ * c_reg + i_ * g_;
        float h = o_ * tanhf_(c_reg);
        ((f16*)&h_lds[urow][0])[uj] = (f16)h;
    };

    // ---- init: zero h, stage W_out into LDS, load enc weights, load x(0) ----
    if (tid < 128) {
        int row = tid >> 6, p = tid & 63;
        f16x2 z; z.x = (f16)0.f; z.y = (f16)0.f;
        h_lds[row][p] = z;
    }
#pragma unroll
    for (int i = 0; i < 16; ++i) {
        int idx = tid * 16 + i;        // 0..4095
        int p = idx >> 6, f = idx & 63;
        wout_lds[p][f] = pack2(Wout[(size_t)f * Hq + 2 * p],
                               Wout[(size_t)f * Hq + 2 * p + 1]);
    }
    load_weights(Wih_e, Whh_e, bih_e, bhh_e);

    if (tid < 64) {
        int row = tid >> 5, p = tid & 31;
        float2 x0 = *(const float2*)(ts + (size_t)(row0 + row) * Tq * Fq + 2 * p);
        x_lds[row][p] = pack2(x0.x, x0.y);
    }
    __syncthreads();

    // ---------------- encoder: 512 steps ----------------
    for (int t = 0; t < Tq; ++t) {
        float2 xn;
        if (tid < 64) {  // prefetch x(t+1), wave 0 only
            int row = tid >> 5, p = tid & 31;
            int tn = (t + 1 < Tq) ? (t + 1) : t;
            xn = *(const float2*)(ts + (size_t)(row0 + row) * Tq * Fq +
                                  (size_t)tn * Fq + 2 * p);
        }
        gates_row(0);
        gates_row(1);
        __syncthreads();
        update_hc();
        if (tid < 64) {
            int row = tid >> 5, p = tid & 31;
            x_lds[row][p] = pack2(xn.x, xn.y);
        }
        __syncthreads();
    }

    // write c_enc
    out[(size_t)(row0 + urow) * Hq + uj] = c_reg;

    // ---------------- switch to decoder ----------------
    load_weights(Wih_d, Whh_d, bih_d, bhh_d);
    float bo = 0.f;
    float err = 0.f;
    float tsv = 0.f;
    if (tid < 128) {
        int row = tid >> 6, f = tid & 63;
        bo = bout[f];
        tsv = ts[(size_t)(row0 + row) * Tq * Fq + (size_t)(Tq - 1) * Fq + f];
    }

    // ---------------- decoder: 512 steps ----------------
    for (int k = 0; k < Tq; ++k) {
        if (tid < 128) {  // waves 0,1: hidden2output projection
            int row = tid >> 6, f = tid & 63;
            float a = bo;
            const f16x2* hp = &h_lds[row][0];
#pragma unroll
            for (int p = 0; p < Hq / 2; ++p)
                a = fdot2f(wout_lds[p][f], hp[p], a);
            if (k == 0)
                out[(size_t)Bq * Hq + Bq + (size_t)(row0 + row) * Fq + f] = a;
            err += fabsf(a * a - tsv * tsv);
            int kn = (k + 1 < Tq) ? (k + 1) : k;
            tsv = ts[(size_t)(row0 + row) * Tq * Fq +
                     (size_t)(Tq - 1 - kn) * Fq + f];
            ((f16*)&x_lds[row][0])[f] = (f16)a;
        }
        __syncthreads();
        gates_row(0);
        gates_row(1);
        __syncthreads();
        update_hc();
        __syncthreads();
    }

    // rec_err: reduce 64 lanes per row (waves 0 and 1 hold rows 0 and 1)
    if (tid < 128) {
        float e = err;
#pragma unroll
        for (int o = 32; o > 0; o >>= 1) e += __shfl_xor(e, o, 64);
        if ((tid & 63) == 0) {
            int row = tid >> 6;
            out[(size_t)Bq * Hq + (row0 + row)] = e;
        }
    }
}

extern "C" void kernel_launch(void* const* d_in, const int* in_sizes, int n_in,
                              void* d_out, int out_size, void* d_ws, size_t ws_size,
                              hipStream_t stream) {
    const float* ts    = (const float*)d_in[0];
    const float* Wih_e = (const float*)d_in[1];
    const float* Whh_e = (const float*)d_in[2];
    const float* bih_e = (const float*)d_in[3];
    const float* bhh_e = (const float*)d_in[4];
    const float* Wih_d = (const float*)d_in[5];
    const float* Whh_d = (const float*)d_in[6];
    const float* bih_d = (const float*)d_in[7];
    const float* bhh_d = (const float*)d_in[8];
    const float* Wout  = (const float*)d_in[9];
    const float* bout  = (const float*)d_in[10];
    float* out = (float*)d_out;

    dim3 grid(Bq / 2);   // 512 blocks, 2 batch rows each
    dim3 block(256);
    hipLaunchKernelGGL(lstm_ae_kernel, grid, block, 0, stream,
                       ts, Wih_e, Whh_e, bih_e, bhh_e,
                       Wih_d, Whh_d, bih_d, bhh_d, Wout, bout, out);
}